// Round 11
// baseline (454.837 us; speedup 1.0000x reference)
//
#include <hip/hip_runtime.h>
#include <math.h>

// ---- problem constants (match reference) ----
static constexpr int NYI  = 256;
static constexpr int PMLW = 20;
static constexpr int NY   = 296, NX = 296;
static constexpr int NCELL = NY * NX;
static constexpr int NS   = 2;
static constexpr int NSRC = 8;
static constexpr int NREC = 64;
static constexpr int NT   = 64;
static constexpr float DXF = 4.0f;
static constexpr float DTF = 5e-4f;
static constexpr float FC1 = 9.0f / 8.0f;
static constexpr float FC2 = -1.0f / 24.0f;
static constexpr float INV_DX = 1.0f / DXF;

// ---- decomposition: 8x8 tiles of 37x37, one shot per block (r7 champion skeleton) ----
static constexpr int TB = 8, TS = 37;          // 8*37 = 296 exactly
static constexpr int VS = TS + 4;              // 41: vel region (tile+2 halo, redundant)
static constexpr int SS = TS + 8;              // 45: stress region (tile+4 halo)
static constexpr int NBLK = TB * TB * NS;      // 128
static constexpr int NTHR = 512;
static constexpr int TAREA = TS * TS;          // 1369
static constexpr int SFRAME = SS * SS - TAREA; // 656 frame cells
// vectorized layout: padded row stride 48 floats (12 float4); 1 thread = 1x4 x-run
static constexpr int LDP   = 48;
static constexpr int NVRUN = 11;               // ceil(41/4) x-runs per V row
static constexpr int NTRUN = 10;               // ceil(37/4) x-runs per tile row
static constexpr int NVT   = VS * NVRUN;       // 451 vel threads
static constexpr int NST   = TS * NTRUN;       // 370 stress threads

// ---- global ws layout (floats): parity-double-buffered stress + per-block flags ----
static constexpr int GSLOT   = 3 * NS * NCELL;
static constexpr int FLG_OFF = 2 * GSLOT;

__device__ __forceinline__ float cohload(const float* p) {
    return __hip_atomic_load(p, __ATOMIC_RELAXED, __HIP_MEMORY_SCOPE_AGENT);
}
__device__ __forceinline__ void cohstore(float* p, float v) {
    __hip_atomic_store(p, v, __ATOMIC_RELAXED, __HIP_MEMORY_SCOPE_AGENT);
}

__global__ __launch_bounds__(NTHR, 1)
void elastic_fused(const float* __restrict__ lamb, const float* __restrict__ mu,
                   const float* __restrict__ buoy, const float* __restrict__ amps,
                   const int* __restrict__ src_loc, const int* __restrict__ rec_loc,
                   float* __restrict__ out, float* __restrict__ ws)
{
    // S logical (sy,sx) in [0,45)^2 covers global (gy0-4+sy, gx0-4+sx); scalar idx sy*48+sx.
    // V logical (vy,vx) in [0,41)^2 covers global (gy0-2+vy, gx0-2+vx); scalar idx vy*48+vx.
    // Tile cell (ty,tx) <-> S (ty+4,tx+4) <-> V (ty+2,tx+2). Runs at x0 % 4 == 0 -> aligned.
    __shared__ float4 sS4[3][SS * (LDP / 4)];   // syy,sxy,sxx
    __shared__ float4 sV4[2][VS * (LDP / 4)];   // vy,vx
    __shared__ __align__(16) float byt[44], ayt[44], bxt[44], axt[44];
    __shared__ float sAmp[NSRC * NT];
    __shared__ float wmax[NTHR / 64];
    __shared__ int   rcnt;
    __shared__ short rl_r[NREC];
    __shared__ int   rl_pos[NREC];

    int* flags = (int*)(ws + FLG_OFF);
    float* gstr = ws;

    const int tid  = threadIdx.x;
    const int shot = blockIdx.x & 1;
    const int tb   = blockIdx.x >> 1;
    const int bty  = tb >> 3, btx = tb & 7;
    const int gy0  = bty * TS, gx0 = btx * TS;
    const int myBlk = blockIdx.x;

    float* S0f = (float*)sS4[0];
    float* S1f = (float*)sS4[1];
    float* S2f = (float*)sS4[2];
    float* V0f = (float*)sV4[0];
    float* V1f = (float*)sV4[1];

    int myNbr = -1;
    if (tid < 8) {
        int idx = tid < 4 ? tid : tid + 1;
        int dy = idx / 3 - 1, dx = idx % 3 - 1;
        int nty = bty + dy, ntx = btx + dx;
        if (nty >= 0 && nty < TB && ntx >= 0 && ntx < TB)
            myNbr = ((nty * TB + ntx) << 1) | shot;
    }

    // ---- zero LDS fields (incl. padding cols; frame t==0 forced 0 below) ----
    for (int i = tid; i < 3 * SS * (LDP / 4); i += NTHR) ((float4*)sS4)[i] = make_float4(0, 0, 0, 0);
    for (int i = tid; i < 2 * VS * (LDP / 4); i += NTHR) ((float4*)sV4)[i] = make_float4(0, 0, 0, 0);
    if (tid == 0) rcnt = 0;

    // ---- block-local global max wave speed (bit-identical per block) ----
    float vmax = 0.0f;
    for (int i = tid * 4; i < NYI * NYI; i += NTHR * 4) {
        const float4 la4 = *(const float4*)(lamb + i);
        const float4 mu4 = *(const float4*)(mu + i);
        const float4 b4  = *(const float4*)(buoy + i);
        vmax = fmaxf(vmax, (la4.x + 2.0f * mu4.x) * b4.x);
        vmax = fmaxf(vmax, (la4.y + 2.0f * mu4.y) * b4.y);
        vmax = fmaxf(vmax, (la4.z + 2.0f * mu4.z) * b4.z);
        vmax = fmaxf(vmax, (la4.w + 2.0f * mu4.w) * b4.w);
    }
    #pragma unroll
    for (int off = 32; off > 0; off >>= 1)
        vmax = fmaxf(vmax, __shfl_down(vmax, off));
    if ((tid & 63) == 0) wmax[tid >> 6] = vmax;

    // ---- vel thread state: one 1x4 run in V; CPML memories + own vy/vx in registers ----
    const bool vthr = tid < NVT;
    int vy_ = 0, vx0 = 0;
    bool vint = false;
    unsigned vmask = 0;
    float buo4[4] = {0, 0, 0, 0};
    int   smk4[4] = {0, 0, 0, 0};
    float m_syyy[4] = {0,0,0,0}, m_sxyx[4] = {0,0,0,0}, m_sxyy[4] = {0,0,0,0}, m_sxxx[4] = {0,0,0,0};
    float rvy[4] = {0,0,0,0}, rvx[4] = {0,0,0,0};
    if (vthr) {
        vy_ = tid / NVRUN; vx0 = (tid - vy_ * NVRUN) * 4;
        int gy = gy0 - 2 + vy_;
        bool rowok = gy >= 0 && gy < NY;
        #pragma unroll
        for (int j = 0; j < 4; ++j) {
            int vx_ = vx0 + j, gx = gx0 - 2 + vx_;
            bool ok = rowok && vx_ < VS && gx >= 0 && gx < NX;
            if (ok) {
                vmask |= 1u << j;
                int iy = min(max(gy - PMLW, 0), NYI - 1);
                int ix = min(max(gx - PMLW, 0), NYI - 1);
                buo4[j] = buoy[iy * NYI + ix];
                #pragma unroll
                for (int s = 0; s < NSRC; ++s) {
                    int sy = src_loc[(shot * NSRC + s) * 2 + 0] + PMLW;
                    int sx = src_loc[(shot * NSRC + s) * 2 + 1] + PMLW;
                    if (sy == gy && sx == gx) smk4[j] |= 1 << s;
                }
            }
        }
        vint = (vy_ >= 4 && vy_ <= 37 && vx0 >= 4 && vx0 + 3 <= 37);
    }

    // ---- stress thread state ----
    const bool sthr = tid < NST;
    int ty = 0, tx0 = 0, gbase = 0;
    unsigned tmask = 0, rmask = 0;
    float lam4[4] = {0,0,0,0}, mu4a[4] = {0,0,0,0}, l2m4[4] = {0,0,0,0};
    float m_vyy[4] = {0,0,0,0}, m_vxx[4] = {0,0,0,0}, m_vyx[4] = {0,0,0,0}, m_vxy[4] = {0,0,0,0};
    float rsyy[4] = {0,0,0,0}, rsxy[4] = {0,0,0,0}, rsxx[4] = {0,0,0,0};
    if (sthr) {
        ty = tid / NTRUN; tx0 = (tid - ty * NTRUN) * 4;
        gbase = (gy0 + ty) * NX + gx0 + tx0;
        #pragma unroll
        for (int j = 0; j < 4; ++j) {
            int tx = tx0 + j;
            if (tx < TS) {
                tmask |= 1u << j;
                if (ty < 4 || ty >= TS - 4 || tx < 4 || tx >= TS - 4) rmask |= 1u << j;
                int gy = gy0 + ty, gx = gx0 + tx;
                int iy = min(max(gy - PMLW, 0), NYI - 1);
                int ix = min(max(gx - PMLW, 0), NYI - 1);
                float la = lamb[iy * NYI + ix], m = mu[iy * NYI + ix];
                lam4[j] = la; mu4a[j] = m; l2m4[j] = la + 2.0f * m;
            }
        }
    }

    // ---- frame-slot geometry (unchanged; new scalar stride) ----
    bool fval[2], fin[2];
    int  flidx[2], fgi[2];
    #pragma unroll
    for (int k = 0; k < 2; ++k) {
        int ff = tid + NTHR * k;
        fval[k] = ff < SFRAME;
        int fy = 0, fx = 0;
        if (fval[k]) {
            if (ff < 4 * SS)      { fy = ff / SS;                 fx = ff - fy * SS; }
            else if (ff < 8 * SS) { int r = ff - 4 * SS; fy = SS - 4 + r / SS; fx = r % SS; }
            else {
                int r = ff - 8 * SS;
                if (r < (SS - 8) * 4) { fy = 4 + (r >> 2); fx = r & 3; }
                else { r -= (SS - 8) * 4; fy = 4 + (r >> 2); fx = SS - 4 + (r & 3); }
            }
        }
        int gy = gy0 - 4 + fy, gx = gx0 - 4 + fx;
        fin[k]   = fval[k] && gy >= 0 && gy < NY && gx >= 0 && gx < NX;
        flidx[k] = fy * LDP + fx;
        fgi[k]   = fin[k] ? (gy * NX + gx) : 0;
    }

    __syncthreads();   // wmax + LDS zeros + rcnt=0 visible

    float vall = wmax[0];
    #pragma unroll
    for (int w = 1; w < NTHR / 64; ++w) vall = fmaxf(vall, wmax[w]);
    const float max_vel = sqrtf(vall);
    const float sig_max = 3.0f * max_vel * logf(1000.0f) / (2.0f * PMLW * DXF);
    if (tid < 44) {
        auto prof = [&](int g) -> float {
            float fi = (float)g;
            float d1 = fmaxf((float)PMLW - fi, 0.0f);
            float d2 = fmaxf(fi - (float)(NY - 1 - PMLW), 0.0f);
            float dd = fmaxf(d1, d2) * (1.0f / (float)PMLW);
            return expf(-(sig_max * dd * dd) * DTF);
        };
        float b = prof(gy0 - 2 + tid); byt[tid] = b; ayt[tid] = b - 1.0f;
        b = prof(gx0 - 2 + tid);       bxt[tid] = b; axt[tid] = b - 1.0f;
    }
    if (tid < NREC) {
        int r = tid;
        int ry = rec_loc[(shot * NREC + r) * 2 + 0] + PMLW;
        int rx = rec_loc[(shot * NREC + r) * 2 + 1] + PMLW;
        if (ry >= gy0 && ry < gy0 + TS && rx >= gx0 && rx < gx0 + TS) {
            int p = atomicAdd(&rcnt, 1);
            rl_r[p]   = (short)r;
            rl_pos[p] = (ry - gy0 + 2) * LDP + (rx - gx0 + 2);
        }
    }
    for (int i = tid; i < NSRC * NT; i += NTHR)
        sAmp[i] = amps[shot * NSRC * NT + i];
    __syncthreads();   // tables + amps + receiver lists visible

    // CPML coeffs to registers once (constant over t)
    float byv = 0, ayv = 0, bxa[4] = {0,0,0,0}, axa[4] = {0,0,0,0};
    if (vthr) {
        byv = byt[vy_]; ayv = ayt[vy_];
        const float4 b4 = *(const float4*)&bxt[vx0];
        const float4 a4 = *(const float4*)&axt[vx0];
        bxa[0] = b4.x; bxa[1] = b4.y; bxa[2] = b4.z; bxa[3] = b4.w;
        axa[0] = a4.x; axa[1] = a4.y; axa[2] = a4.z; axa[3] = a4.w;
    }
    float byS = 0, ayS = 0, bxS[4] = {0,0,0,0}, axS[4] = {0,0,0,0};
    if (sthr) {
        byS = byt[ty + 2]; ayS = ayt[ty + 2];
        #pragma unroll
        for (int j = 0; j < 4; ++j) { bxS[j] = bxt[tx0 + 2 + j]; axS[j] = axt[tx0 + 2 + j]; }
    }

    // ---- vel body: 4 cells, vectorized LDS reads (2xb128 per x-field, b64 pairs per y-row) ----
    auto vel_body = [&](int t) {
        const int rb2 = (vy_ + 2) * LDP + vx0;          // S row vy_+2, col vx0 (float4-aligned)
        const float4 A = *(const float4*)(S1f + rb2);
        const float4 B = *(const float4*)(S1f + rb2 + 4);
        const float4 C = *(const float4*)(S2f + rb2);
        const float4 D = *(const float4*)(S2f + rb2 + 4);
        const float a8[8] = {A.x, A.y, A.z, A.w, B.x, B.y, B.z, B.w};
        const float c8[8] = {C.x, C.y, C.z, C.w, D.x, D.y, D.z, D.w};
        float sy0[4], sy1[4], sy2[4], sy3[4];           // syy rows vy_..vy_+3, cols vx0+2..+5
        float xy0[4], xy1[4], xy3[4];                   // sxy rows vy_+0,+1,+3 (row +2 = a8)
        {
            const int cb = vx0 + 2;
            float2 p, q;
            p = *(const float2*)(S0f + (vy_ + 0) * LDP + cb); q = *(const float2*)(S0f + (vy_ + 0) * LDP + cb + 2);
            sy0[0] = p.x; sy0[1] = p.y; sy0[2] = q.x; sy0[3] = q.y;
            p = *(const float2*)(S0f + (vy_ + 1) * LDP + cb); q = *(const float2*)(S0f + (vy_ + 1) * LDP + cb + 2);
            sy1[0] = p.x; sy1[1] = p.y; sy1[2] = q.x; sy1[3] = q.y;
            p = *(const float2*)(S0f + (vy_ + 2) * LDP + cb); q = *(const float2*)(S0f + (vy_ + 2) * LDP + cb + 2);
            sy2[0] = p.x; sy2[1] = p.y; sy2[2] = q.x; sy2[3] = q.y;
            p = *(const float2*)(S0f + (vy_ + 3) * LDP + cb); q = *(const float2*)(S0f + (vy_ + 3) * LDP + cb + 2);
            sy3[0] = p.x; sy3[1] = p.y; sy3[2] = q.x; sy3[3] = q.y;
            p = *(const float2*)(S1f + (vy_ + 0) * LDP + cb); q = *(const float2*)(S1f + (vy_ + 0) * LDP + cb + 2);
            xy0[0] = p.x; xy0[1] = p.y; xy0[2] = q.x; xy0[3] = q.y;
            p = *(const float2*)(S1f + (vy_ + 1) * LDP + cb); q = *(const float2*)(S1f + (vy_ + 1) * LDP + cb + 2);
            xy1[0] = p.x; xy1[1] = p.y; xy1[2] = q.x; xy1[3] = q.y;
            p = *(const float2*)(S1f + (vy_ + 3) * LDP + cb); q = *(const float2*)(S1f + (vy_ + 3) * LDP + cb + 2);
            xy3[0] = p.x; xy3[1] = p.y; xy3[2] = q.x; xy3[3] = q.y;
        }
        #pragma unroll
        for (int j = 0; j < 4; ++j) {
            float nvy = 0.0f, nvx = 0.0f;
            if (vmask & (1u << j)) {
                float d, mm;
                // d/dy- syy  (f[y]=sy2, f[y-1]=sy1, f[y+1]=sy3, f[y-2]=sy0)
                d = (FC1 * (sy2[j] - sy1[j]) + FC2 * (sy3[j] - sy0[j])) * INV_DX;
                mm = byv * m_syyy[j] + ayv * d;  m_syyy[j] = mm;  float dsyy_y = d + mm;
                // d/dx- sxy  (center S-x = vx0+2+j -> a8[j+2])
                d = (FC1 * (a8[j + 2] - a8[j + 1]) + FC2 * (a8[j + 3] - a8[j])) * INV_DX;
                mm = bxa[j] * m_sxyx[j] + axa[j] * d;  m_sxyx[j] = mm;  float dsxy_x = d + mm;
                nvy = rvy[j] + DTF * buo4[j] * (dsyy_y + dsxy_x);
                // d/dy- sxy  (f[y]=a8[j+2] row vy_+2)
                d = (FC1 * (a8[j + 2] - xy1[j]) + FC2 * (xy3[j] - xy0[j])) * INV_DX;
                mm = byv * m_sxyy[j] + ayv * d;  m_sxyy[j] = mm;  float dsxy_y = d + mm;
                // d/dx- sxx
                d = (FC1 * (c8[j + 2] - c8[j + 1]) + FC2 * (c8[j + 3] - c8[j])) * INV_DX;
                mm = bxa[j] * m_sxxx[j] + axa[j] * d;  m_sxxx[j] = mm;  float dsxx_x = d + mm;
                nvx = rvx[j] + DTF * buo4[j] * (dsxy_y + dsxx_x);
                if (smk4[j]) {
                    #pragma unroll
                    for (int s = 0; s < NSRC; ++s)
                        if ((smk4[j] >> s) & 1) nvy += DTF * buo4[j] * sAmp[s * NT + t];
                }
            }
            rvy[j] = nvy; rvx[j] = nvx;
        }
        *(float4*)(V0f + vy_ * LDP + vx0) = make_float4(rvy[0], rvy[1], rvy[2], rvy[3]);
        *(float4*)(V1f + vy_ * LDP + vx0) = make_float4(rvx[0], rvx[1], rvx[2], rvx[3]);
    };

    // ---- stress body: 4 cells, vectorized; ring cells publish inline; state in registers ----
    auto str_body = [&](int t, float* gsw) {
        const int rb2 = (ty + 2) * LDP + tx0;           // V row ty+2, col tx0 (aligned)
        const float4 A = *(const float4*)(V0f + rb2);
        const float4 B = *(const float4*)(V0f + rb2 + 4);
        const float4 C = *(const float4*)(V1f + rb2);
        const float4 D = *(const float4*)(V1f + rb2 + 4);
        const float a8[8] = {A.x, A.y, A.z, A.w, B.x, B.y, B.z, B.w};  // vy row ty+2
        const float c8[8] = {C.x, C.y, C.z, C.w, D.x, D.y, D.z, D.w};  // vx row ty+2
        float vyr0[4], vyr2[4], vyr3[4];   // vy rows ty+1, ty+3, ty+4 at cols tx0+2..+5
        float vxr0[4], vxr2[4], vxr3[4];
        {
            const int cb = tx0 + 2;
            float2 p, q;
            p = *(const float2*)(V0f + (ty + 1) * LDP + cb); q = *(const float2*)(V0f + (ty + 1) * LDP + cb + 2);
            vyr0[0] = p.x; vyr0[1] = p.y; vyr0[2] = q.x; vyr0[3] = q.y;
            p = *(const float2*)(V0f + (ty + 3) * LDP + cb); q = *(const float2*)(V0f + (ty + 3) * LDP + cb + 2);
            vyr2[0] = p.x; vyr2[1] = p.y; vyr2[2] = q.x; vyr2[3] = q.y;
            p = *(const float2*)(V0f + (ty + 4) * LDP + cb); q = *(const float2*)(V0f + (ty + 4) * LDP + cb + 2);
            vyr3[0] = p.x; vyr3[1] = p.y; vyr3[2] = q.x; vyr3[3] = q.y;
            p = *(const float2*)(V1f + (ty + 1) * LDP + cb); q = *(const float2*)(V1f + (ty + 1) * LDP + cb + 2);
            vxr0[0] = p.x; vxr0[1] = p.y; vxr0[2] = q.x; vxr0[3] = q.y;
            p = *(const float2*)(V1f + (ty + 3) * LDP + cb); q = *(const float2*)(V1f + (ty + 3) * LDP + cb + 2);
            vxr2[0] = p.x; vxr2[1] = p.y; vxr2[2] = q.x; vxr2[3] = q.y;
            p = *(const float2*)(V1f + (ty + 4) * LDP + cb); q = *(const float2*)(V1f + (ty + 4) * LDP + cb + 2);
            vxr3[0] = p.x; vxr3[1] = p.y; vxr3[2] = q.x; vxr3[3] = q.y;
        }
        #pragma unroll
        for (int j = 0; j < 4; ++j) {
            if (!(tmask & (1u << j))) continue;
            float d, mm;
            // d/dy+ vy  (f[y]=a8[j+2] row ty+2; f[y+1]=vyr2; f[y+2]=vyr3; f[y-1]=vyr0)
            d = (FC1 * (vyr2[j] - a8[j + 2]) + FC2 * (vyr3[j] - vyr0[j])) * INV_DX;
            mm = byS * m_vyy[j] + ayS * d;  m_vyy[j] = mm;  float dvy_y = d + mm;
            // d/dx+ vx  (f[x]=c8[j+2]; f[x+1]=c8[j+3]; f[x+2]=c8[j+4]; f[x-1]=c8[j+1])
            d = (FC1 * (c8[j + 3] - c8[j + 2]) + FC2 * (c8[j + 4] - c8[j + 1])) * INV_DX;
            mm = bxS[j] * m_vxx[j] + axS[j] * d;  m_vxx[j] = mm;  float dvx_x = d + mm;
            float nsyy = rsyy[j] + DTF * (l2m4[j] * dvy_y + lam4[j] * dvx_x);
            float nsxx = rsxx[j] + DTF * (lam4[j] * dvy_y + l2m4[j] * dvx_x);
            // d/dx+ vy
            d = (FC1 * (a8[j + 3] - a8[j + 2]) + FC2 * (a8[j + 4] - a8[j + 1])) * INV_DX;
            mm = bxS[j] * m_vyx[j] + axS[j] * d;  m_vyx[j] = mm;  float dvy_x = d + mm;
            // d/dy+ vx
            d = (FC1 * (vxr2[j] - c8[j + 2]) + FC2 * (vxr3[j] - vxr0[j])) * INV_DX;
            mm = byS * m_vxy[j] + ayS * d;  m_vxy[j] = mm;  float dvx_y = d + mm;
            float nsxy = rsxy[j] + DTF * mu4a[j] * (dvy_x + dvx_y);
            rsyy[j] = nsyy; rsxy[j] = nsxy; rsxx[j] = nsxx;
            if (rmask & (1u << j)) {
                int gi = gbase + j;
                cohstore(&gsw[(0 * NS + shot) * NCELL + gi], nsyy);
                cohstore(&gsw[(1 * NS + shot) * NCELL + gi], nsxy);
                cohstore(&gsw[(2 * NS + shot) * NCELL + gi], nsxx);
            }
        }
        const int so = (ty + 4) * LDP + tx0 + 4;        // S row ty+4, col tx0+4 (aligned)
        *(float4*)(S0f + so) = make_float4(rsyy[0], rsyy[1], rsyy[2], rsyy[3]);
        *(float4*)(S1f + so) = make_float4(rsxy[0], rsxy[1], rsxy[2], rsxy[3]);
        *(float4*)(S2f + so) = make_float4(rsxx[0], rsxx[1], rsxx[2], rsxx[3]);
    };

    // ========== time loop: r7 skeleton (neighbor flags, interior vel pre-wait) ==========
    for (int t = 0; t < NT; ++t) {
        const float* gsr = gstr + ((t + 1) & 1) * GSLOT;   // neighbors' state(t-1)
        float*       gsw = gstr + (t & 1) * GSLOT;         // my state(t)

        // interior velocity: no frame dependency -> overlaps neighbor drift
        if (vthr && vint) vel_body(t);

        // wait: my 8 neighbors must have published ring(t-1)
        if (t > 0 && myNbr >= 0) {
            while (__hip_atomic_load(&flags[myNbr], __ATOMIC_RELAXED,
                                     __HIP_MEMORY_SCOPE_AGENT) < t)
                __builtin_amdgcn_s_sleep(1);
        }
        __syncthreads();

        // frame loads (6 sc1 loads, clustered) -> LDS frame
        float fr0[3], fr1[3];
        #pragma unroll
        for (int f = 0; f < 3; ++f) {
            fr0[f] = (t > 0 && fin[0]) ? cohload(&gsr[(f * NS + shot) * NCELL + fgi[0]]) : 0.0f;
            fr1[f] = (t > 0 && fin[1]) ? cohload(&gsr[(f * NS + shot) * NCELL + fgi[1]]) : 0.0f;
        }
        if (fval[0]) { S0f[flidx[0]] = fr0[0]; S1f[flidx[0]] = fr0[1]; S2f[flidx[0]] = fr0[2]; }
        if (fval[1]) { S0f[flidx[1]] = fr1[0]; S1f[flidx[1]] = fr1[1]; S2f[flidx[1]] = fr1[2]; }
        __syncthreads();

        // boundary velocity (needs frame)
        if (vthr && !vint) vel_body(t);
        __syncthreads();

        // receivers: vy after injection (LDS-resident)
        if (tid < rcnt)
            out[(shot * NREC + rl_r[tid]) * NT + t] = V0f[rl_pos[tid]];

        // stress on tile; ring cells published inline
        if (sthr) str_body(t, gsw);

        // publish: syncthreads drains all waves' ring stores (vmcnt(0)) -> flag store
        __syncthreads();
        if (tid == 0 && t < NT - 1)
            __hip_atomic_store(&flags[myBlk], t + 1, __ATOMIC_RELAXED,
                               __HIP_MEMORY_SCOPE_AGENT);
    }
}

extern "C" void kernel_launch(void* const* d_in, const int* in_sizes, int n_in,
                              void* d_out, int out_size, void* d_ws, size_t ws_size,
                              hipStream_t stream) {
    const float* lamb    = (const float*)d_in[0];
    const float* mu      = (const float*)d_in[1];
    const float* buoy    = (const float*)d_in[2];
    const float* amps    = (const float*)d_in[3];
    const int*   src_loc = (const int*)d_in[4];
    const int*   rec_loc = (const int*)d_in[5];
    float* ws  = (float*)d_ws;
    float* out = (float*)d_out;

    // zero per-block publish flags (ws is poisoned 0xAA before every call)
    hipMemsetAsync(ws + FLG_OFF, 0, NBLK * sizeof(int), stream);

    elastic_fused<<<NBLK, NTHR, 0, stream>>>(lamb, mu, buoy, amps, src_loc, rec_loc, out, ws);
}

// Round 12
// 342.860 us; speedup vs baseline: 1.3266x; 1.3266x over previous
//
#include <hip/hip_runtime.h>
#include <math.h>

// ---- problem constants (match reference) ----
static constexpr int NYI  = 256;
static constexpr int PMLW = 20;
static constexpr int NY   = 296, NX = 296;
static constexpr int NCELL = NY * NX;
static constexpr int NS   = 2;
static constexpr int NSRC = 8;
static constexpr int NREC = 64;
static constexpr int NT   = 64;
static constexpr float DXF = 4.0f;
static constexpr float DTF = 5e-4f;
static constexpr float FC1 = 9.0f / 8.0f;
static constexpr float FC2 = -1.0f / 24.0f;
static constexpr float INV_DX = 1.0f / DXF;

// ---- decomposition: 8x8 tiles of 37x37, one shot per block (round-7 champion) ----
static constexpr int TB = 8, TS = 37;          // 8*37 = 296 exactly
static constexpr int VS = TS + 4;              // 41: vel region (tile+2 halo, redundant)
static constexpr int SS = TS + 8;              // 45: stress region (tile+4 halo)
static constexpr int NBLK = TB * TB * NS;      // 128
static constexpr int NTHR = 512;
static constexpr int VAREA = VS * VS;          // 1681
static constexpr int TAREA = TS * TS;          // 1369
static constexpr int SFRAME = SS * SS - TAREA; // 656 frame cells
static constexpr int KV = 4, KT = 3;

// ---- global ws layout (floats): parity-double-buffered stress + per-block flags ----
static constexpr int GSLOT   = 3 * NS * NCELL;       // one parity buffer
static constexpr int FLG_OFF = 2 * GSLOT;            // int flags[NBLK]: steps published

__device__ __forceinline__ float cohload(const float* p) {
    return __hip_atomic_load(p, __ATOMIC_RELAXED, __HIP_MEMORY_SCOPE_AGENT);
}
__device__ __forceinline__ void cohstore(float* p, float v) {
    __hip_atomic_store(p, v, __ATOMIC_RELAXED, __HIP_MEMORY_SCOPE_AGENT);
}

__global__ __launch_bounds__(NTHR, 1)
void elastic_fused(const float* __restrict__ lamb, const float* __restrict__ mu,
                   const float* __restrict__ buoy, const float* __restrict__ amps,
                   const int* __restrict__ src_loc, const int* __restrict__ rec_loc,
                   float* __restrict__ out, float* __restrict__ ws)
{
    __shared__ float sS[3][SS * SS];     // syy,sxy,sxx  (center computed, frame from neighbors)
    __shared__ float sV[2][VS * VS];     // vy,vx        (all computed locally, halo redundant)
    __shared__ float byt[VS], ayt[VS], bxt[VS], axt[VS];
    __shared__ float sAmp[NSRC * NT];
    __shared__ float wmax[NTHR / 64];
    __shared__ int   rcnt;
    __shared__ short rl_r[NREC];
    __shared__ int   rl_pos[NREC];

    int* flags = (int*)(ws + FLG_OFF);
    float* gstr = ws;

    const int tid  = threadIdx.x;
    const int shot = blockIdx.x & 1;
    const int tb   = blockIdx.x >> 1;
    const int bty  = tb >> 3, btx = tb & 7;
    const int gy0  = bty * TS, gx0 = btx * TS;
    const int myBlk = blockIdx.x;

    // poll thread -> one spatial neighbor (same shot); frame touches corners, so all 8
    int myNbr = -1;
    if (tid < 8) {
        int idx = tid < 4 ? tid : tid + 1;          // skip center of 3x3
        int dy = idx / 3 - 1, dx = idx % 3 - 1;
        int nty = bty + dy, ntx = btx + dx;
        if (nty >= 0 && nty < TB && ntx >= 0 && ntx < TB)
            myNbr = ((nty * TB + ntx) << 1) | shot;
    }

    // ---- zero LDS fields (global stress buffers need NO init: t==0 frame stays zero) ----
    for (int i = tid; i < 3 * SS * SS; i += NTHR) ((float*)sS)[i] = 0.0f;
    for (int i = tid; i < 2 * VS * VS; i += NTHR) ((float*)sV)[i] = 0.0f;
    if (tid == 0) rcnt = 0;

    // ---- block-local global max wave speed (bit-identical per block;
    //      max is order-free, sqrt monotone => sqrt(max) == max(sqrt)) ----
    float vmax = 0.0f;
    for (int i = tid * 4; i < NYI * NYI; i += NTHR * 4) {
        const float4 la4 = *(const float4*)(lamb + i);
        const float4 mu4 = *(const float4*)(mu + i);
        const float4 b4  = *(const float4*)(buoy + i);
        vmax = fmaxf(vmax, (la4.x + 2.0f * mu4.x) * b4.x);
        vmax = fmaxf(vmax, (la4.y + 2.0f * mu4.y) * b4.y);
        vmax = fmaxf(vmax, (la4.z + 2.0f * mu4.z) * b4.z);
        vmax = fmaxf(vmax, (la4.w + 2.0f * mu4.w) * b4.w);
    }
    #pragma unroll
    for (int off = 32; off > 0; off >>= 1)
        vmax = fmaxf(vmax, __shfl_down(vmax, off));
    if ((tid & 63) == 0) wmax[tid >> 6] = vmax;

    // ---- per-thread V-region slots (vel + its CPML memories, redundant halo-2) ----
    int   sidx_v[KV], vyv[KV], vxv[KV], smk[KV];
    float buo_v[KV];
    float msyyy[KV] = {0,0,0,0}, msxyx[KV] = {0,0,0,0};
    float msxyy[KV] = {0,0,0,0}, msxxx[KV] = {0,0,0,0};
    unsigned cvm = 0, intm = 0;
    #pragma unroll
    for (int k = 0; k < KV; ++k) {
        int vi = tid + NTHR * k;
        bool val = vi < VAREA;
        int vy_ = val ? vi / VS : 0;
        int vx_ = val ? vi - vy_ * VS : 0;
        int gy = gy0 - 2 + vy_, gx = gx0 - 2 + vx_;
        bool ing = val && gy >= 0 && gy < NY && gx >= 0 && gx < NX;
        if (ing) cvm |= 1u << k;
        // interior vel: S-stencil rows [vy,vy+3], cols [vx,vx+3] all inside center [4,41)
        if (ing && vy_ >= 4 && vy_ <= 37 && vx_ >= 4 && vx_ <= 37) intm |= 1u << k;
        vyv[k] = vy_; vxv[k] = vx_;
        sidx_v[k] = (vy_ + 2) * SS + (vx_ + 2);
        float b = 0.0f;
        if (ing) {
            int iy = min(max(gy - PMLW, 0), NYI - 1);
            int ix = min(max(gx - PMLW, 0), NYI - 1);
            b = buoy[iy * NYI + ix];
        }
        buo_v[k] = b;
        int sm = 0;
        #pragma unroll
        for (int s = 0; s < NSRC; ++s) {
            int sy = src_loc[(shot * NSRC + s) * 2 + 0] + PMLW;
            int sx = src_loc[(shot * NSRC + s) * 2 + 1] + PMLW;
            if (ing && sy == gy && sx == gx) sm |= 1 << s;
        }
        smk[k] = sm;
    }
    const unsigned bndm = cvm & ~intm;

    // ---- per-thread tile slots (stress + its CPML memories, owned) ----
    int   sidx_t[KT], vidx_t[KT], gidx_t[KT], tyt[KT], txt[KT];
    float lam_t[KT], mu_t[KT], l2m_t[KT];
    float mvyy[KT] = {0,0,0}, mvxx[KT] = {0,0,0}, mvyx[KT] = {0,0,0}, mvxy[KT] = {0,0,0};
    unsigned ctm = 0, ringm = 0;
    #pragma unroll
    for (int k = 0; k < KT; ++k) {
        int ti = tid + NTHR * k;
        bool val = ti < TAREA;
        int ty = val ? ti / TS : 0;
        int tx = val ? ti - ty * TS : 0;
        int gy = gy0 + ty, gx = gx0 + tx;
        if (val) ctm |= 1u << k;
        if (val && (ty < 4 || ty >= TS - 4 || tx < 4 || tx >= TS - 4)) ringm |= 1u << k;
        tyt[k] = ty; txt[k] = tx;
        sidx_t[k] = (ty + 4) * SS + (tx + 4);
        vidx_t[k] = (ty + 2) * VS + (tx + 2);
        gidx_t[k] = gy * NX + gx;
        float la = 0.0f, m = 0.0f;
        if (val) {
            int iy = min(max(gy - PMLW, 0), NYI - 1);
            int ix = min(max(gx - PMLW, 0), NYI - 1);
            la = lamb[iy * NYI + ix];
            m  = mu  [iy * NYI + ix];
        }
        lam_t[k] = la; mu_t[k] = m; l2m_t[k] = la + 2.0f * m;
    }

    // ---- per-thread frame-slot geometry ----
    bool fval[2], fin[2];
    int  flidx[2], fgi[2];
    #pragma unroll
    for (int k = 0; k < 2; ++k) {
        int ff = tid + NTHR * k;
        fval[k] = ff < SFRAME;
        int fy = 0, fx = 0;
        if (fval[k]) {
            if (ff < 4 * SS)      { fy = ff / SS;                 fx = ff - fy * SS; }
            else if (ff < 8 * SS) { int r = ff - 4 * SS; fy = SS - 4 + r / SS; fx = r % SS; }
            else {
                int r = ff - 8 * SS;
                if (r < (SS - 8) * 4) { fy = 4 + (r >> 2); fx = r & 3; }
                else { r -= (SS - 8) * 4; fy = 4 + (r >> 2); fx = SS - 4 + (r & 3); }
            }
        }
        int gy = gy0 - 4 + fy, gx = gx0 - 4 + fx;
        fin[k]   = fval[k] && gy >= 0 && gy < NY && gx >= 0 && gx < NX;
        flidx[k] = fy * SS + fx;
        fgi[k]   = fin[k] ? (gy * NX + gx) : 0;
    }

    __syncthreads();   // wmax + LDS zeros + rcnt=0 visible in-block

    float vall = wmax[0];
    #pragma unroll
    for (int w = 1; w < NTHR / 64; ++w) vall = fmaxf(vall, wmax[w]);
    const float max_vel = sqrtf(vall);
    const float sig_max = 3.0f * max_vel * logf(1000.0f) / (2.0f * PMLW * DXF);
    if (tid < VS) {
        auto prof = [&](int g) -> float {
            float fi = (float)g;
            float d1 = fmaxf((float)PMLW - fi, 0.0f);
            float d2 = fmaxf(fi - (float)(NY - 1 - PMLW), 0.0f);
            float dd = fmaxf(d1, d2) * (1.0f / (float)PMLW);
            return expf(-(sig_max * dd * dd) * DTF);
        };
        float b = prof(gy0 - 2 + tid); byt[tid] = b; ayt[tid] = b - 1.0f;
        b = prof(gx0 - 2 + tid);       bxt[tid] = b; axt[tid] = b - 1.0f;
    }
    if (tid < NREC) {
        int r = tid;
        int ry = rec_loc[(shot * NREC + r) * 2 + 0] + PMLW;
        int rx = rec_loc[(shot * NREC + r) * 2 + 1] + PMLW;
        if (ry >= gy0 && ry < gy0 + TS && rx >= gx0 && rx < gx0 + TS) {
            int p = atomicAdd(&rcnt, 1);
            rl_r[p]   = (short)r;
            rl_pos[p] = (ry - gy0 + 2) * VS + (rx - gx0 + 2);
        }
    }
    for (int i = tid; i < NSRC * NT; i += NTHR)
        sAmp[i] = amps[shot * NSRC * NT + i];
    __syncthreads();   // tables + amps + receiver lists visible

    // velocity body over a slot mask (interior runs pre-wait, boundary post-frame-fill)
    auto do_vel = [&](unsigned m, int t) {
        #pragma unroll
        for (int k = 0; k < KV; ++k) {
            if (!((m >> k) & 1)) continue;
            int si = sidx_v[k];
            float by_ = byt[vyv[k]], ay_ = ayt[vyv[k]];
            float bx_ = bxt[vxv[k]], ax_ = axt[vxv[k]];
            float d, mm;
            d = (FC1 * (sS[0][si] - sS[0][si - SS]) + FC2 * (sS[0][si + SS] - sS[0][si - 2 * SS])) * INV_DX;
            mm = by_ * msyyy[k] + ay_ * d;  msyyy[k] = mm;  float dsyy_y = d + mm;
            d = (FC1 * (sS[1][si] - sS[1][si - 1]) + FC2 * (sS[1][si + 1] - sS[1][si - 2])) * INV_DX;
            mm = bx_ * msxyx[k] + ax_ * d;  msxyx[k] = mm;  float dsxy_x = d + mm;
            d = (FC1 * (sS[1][si] - sS[1][si - SS]) + FC2 * (sS[1][si + SS] - sS[1][si - 2 * SS])) * INV_DX;
            mm = by_ * msxyy[k] + ay_ * d;  msxyy[k] = mm;  float dsxy_y = d + mm;
            d = (FC1 * (sS[2][si] - sS[2][si - 1]) + FC2 * (sS[2][si + 1] - sS[2][si - 2])) * INV_DX;
            mm = bx_ * msxxx[k] + ax_ * d;  msxxx[k] = mm;  float dsxx_x = d + mm;
            int vi = tid + NTHR * k;   // sV flat index == V row-major index
            float nvy = sV[0][vi] + DTF * buo_v[k] * (dsyy_y + dsxy_x);
            float nvx = sV[1][vi] + DTF * buo_v[k] * (dsxy_y + dsxx_x);
            if (smk[k]) {
                #pragma unroll
                for (int s = 0; s < NSRC; ++s)
                    if ((smk[k] >> s) & 1) nvy += DTF * buo_v[k] * sAmp[s * NT + t];
            }
            sV[0][vi] = nvy;
            sV[1][vi] = nvx;
        }
    };

    // ========== time loop: neighbor-flag sync only (round-7 structure) ==========
    // flag[b] = #steps b has published. Skew between neighbors <= 1 step, so the
    // parity double-buffer separates readers/writers.
    for (int t = 0; t < NT; ++t) {
        const float* gsr = gstr + ((t + 1) & 1) * GSLOT;   // neighbors' state(t-1)
        float*       gsw = gstr + (t & 1) * GSLOT;         // my state(t)

        // interior velocity: no frame dependency -> overlaps neighbor drift
        do_vel(intm, t);

        // wait: my 8 neighbors must have published ring(t-1)
        if (t > 0 && myNbr >= 0) {
            while (__hip_atomic_load(&flags[myNbr], __ATOMIC_RELAXED,
                                     __HIP_MEMORY_SCOPE_AGENT) < t)
                __builtin_amdgcn_s_sleep(1);
        }
        __syncthreads();

        // P1: frame loads (6 sc1 loads, clustered) -> LDS frame
        float fr0[3], fr1[3];
        #pragma unroll
        for (int f = 0; f < 3; ++f) {
            fr0[f] = (t > 0 && fin[0]) ? cohload(&gsr[(f * NS + shot) * NCELL + fgi[0]]) : 0.0f;
            fr1[f] = (t > 0 && fin[1]) ? cohload(&gsr[(f * NS + shot) * NCELL + fgi[1]]) : 0.0f;
        }
        if (fval[0]) { sS[0][flidx[0]] = fr0[0]; sS[1][flidx[0]] = fr0[1]; sS[2][flidx[0]] = fr0[2]; }
        if (fval[1]) { sS[0][flidx[1]] = fr1[0]; sS[1][flidx[1]] = fr1[1]; sS[2][flidx[1]] = fr1[2]; }
        __syncthreads();

        // boundary velocity (needs frame)
        do_vel(bndm, t);
        __syncthreads();

        // receivers: vy after injection (LDS-resident)
        if (tid < rcnt)
            out[(shot * NREC + rl_r[tid]) * NT + t] = sV[0][rl_pos[tid]];

        // stress on tile; ring cells published immediately (same thread owns both)
        #pragma unroll
        for (int k = 0; k < KT; ++k) {
            if (!((ctm >> k) & 1)) continue;
            int si = sidx_t[k], vi = vidx_t[k];
            float by_ = byt[tyt[k] + 2], ay_ = ayt[tyt[k] + 2];
            float bx_ = bxt[txt[k] + 2], ax_ = axt[txt[k] + 2];
            float d, mm;
            d = (FC1 * (sV[0][vi + VS] - sV[0][vi]) + FC2 * (sV[0][vi + 2 * VS] - sV[0][vi - VS])) * INV_DX;
            mm = by_ * mvyy[k] + ay_ * d;  mvyy[k] = mm;  float dvy_y = d + mm;
            d = (FC1 * (sV[1][vi + 1] - sV[1][vi]) + FC2 * (sV[1][vi + 2] - sV[1][vi - 1])) * INV_DX;
            mm = bx_ * mvxx[k] + ax_ * d;  mvxx[k] = mm;  float dvx_x = d + mm;
            float nsyy = sS[0][si] + DTF * (l2m_t[k] * dvy_y + lam_t[k] * dvx_x);
            float nsxx = sS[2][si] + DTF * (lam_t[k] * dvy_y + l2m_t[k] * dvx_x);
            d = (FC1 * (sV[0][vi + 1] - sV[0][vi]) + FC2 * (sV[0][vi + 2] - sV[0][vi - 1])) * INV_DX;
            mm = bx_ * mvyx[k] + ax_ * d;  mvyx[k] = mm;  float dvy_x = d + mm;
            d = (FC1 * (sV[1][vi + VS] - sV[1][vi]) + FC2 * (sV[1][vi + 2 * VS] - sV[1][vi - VS])) * INV_DX;
            mm = by_ * mvxy[k] + ay_ * d;  mvxy[k] = mm;  float dvx_y = d + mm;
            float nsxy = sS[1][si] + DTF * mu_t[k] * (dvy_x + dvx_y);
            sS[0][si] = nsyy; sS[1][si] = nsxy; sS[2][si] = nsxx;
            if ((ringm >> k) & 1) {
                int gi = gidx_t[k];
                cohstore(&gsw[(0 * NS + shot) * NCELL + gi], nsyy);
                cohstore(&gsw[(1 * NS + shot) * NCELL + gi], nsxy);
                cohstore(&gsw[(2 * NS + shot) * NCELL + gi], nsxx);
            }
        }

        // publish: syncthreads drains all waves' ring stores (vmcnt(0)) -> flag store
        __syncthreads();
        if (tid == 0 && t < NT - 1)
            __hip_atomic_store(&flags[myBlk], t + 1, __ATOMIC_RELAXED,
                               __HIP_MEMORY_SCOPE_AGENT);
    }
}

extern "C" void kernel_launch(void* const* d_in, const int* in_sizes, int n_in,
                              void* d_out, int out_size, void* d_ws, size_t ws_size,
                              hipStream_t stream) {
    const float* lamb    = (const float*)d_in[0];
    const float* mu      = (const float*)d_in[1];
    const float* buoy    = (const float*)d_in[2];
    const float* amps    = (const float*)d_in[3];
    const int*   src_loc = (const int*)d_in[4];
    const int*   rec_loc = (const int*)d_in[5];
    float* ws  = (float*)d_ws;
    float* out = (float*)d_out;

    // zero per-block publish flags (ws is poisoned 0xAA before every call)
    hipMemsetAsync(ws + FLG_OFF, 0, NBLK * sizeof(int), stream);

    elastic_fused<<<NBLK, NTHR, 0, stream>>>(lamb, mu, buoy, amps, src_loc, rec_loc, out, ws);
}